// Round 3
// baseline (6409.142 us; speedup 1.0000x reference)
//
#include <hip/hip_runtime.h>

// NeuralODE fused persistent kernel v8 (MI355X / gfx950).
// v7 -> v8: PHASE-OFFSET scheduling. 8 waves = 2 groups x 2 pairs x 2 halves.
// Group 1 (wid 4..7) runs one phase ahead of group 0 (wid 0..3). Each SIMD
// hosts one wave of each group -> per slot one wave is in gemm2 (MFMA-heavy)
// while the other is in gemm1 (VALU/tanh-heavy); pipes interleave instead of
// colliding. Schedule is flattened to a phase counter (66 phases/interval:
// 8 substeps x 8 + 2 epilogue), one __syncthreads per slot (same barrier
// count as v7). Pair-private h/k LDS buffers make cross-group drift safe.

typedef _Float16 f16;
typedef _Float16 f16x4 __attribute__((ext_vector_type(4)));
typedef _Float16 f16x8 __attribute__((ext_vector_type(8)));
typedef float    f32x4 __attribute__((ext_vector_type(4)));

#define MFMA(a, b, c) __builtin_amdgcn_mfma_f32_16x16x32_f16((a), (b), (c), 0, 0, 0)

static __device__ __forceinline__ float fast_tanh(float x) {
    // 1 - 2/(1+exp2(2*log2e*x)); e=inf -> rcp(inf)=0 -> 1.0 (safe)
    float e = __builtin_amdgcn_exp2f(x * 2.885390081777927f);
    float r = __builtin_amdgcn_rcpf(e + 1.0f);
    return __builtin_fmaf(-2.0f, r, 1.0f);
}

// f32 -> (f16 hi, f16 lo) compensated split of 4 values via packed rtz cvt.
static __device__ __forceinline__ void split4(float t0, float t1, float t2, float t3,
                                              f16x4* hv, f16x4* lv) {
    auto h01 = __builtin_amdgcn_cvt_pkrtz(t0, t1);
    auto h23 = __builtin_amdgcn_cvt_pkrtz(t2, t3);
    float l0 = t0 - (float)h01[0], l1 = t1 - (float)h01[1];
    float l2 = t2 - (float)h23[0], l3 = t3 - (float)h23[1];
    auto s01 = __builtin_amdgcn_cvt_pkrtz(l0, l1);
    auto s23 = __builtin_amdgcn_cvt_pkrtz(l2, l3);
    f16x4 h, l;
    h[0] = h01[0]; h[1] = h01[1]; h[2] = h23[0]; h[3] = h23[1];
    l[0] = s01[0]; l[1] = s01[1]; l[2] = s23[0]; l[3] = s23[1];
    *hv = h; *lv = l;
}

__global__ __launch_bounds__(512, 2) void node_fused(
    const float* __restrict__ y0g, const float* __restrict__ tg,
    const float* __restrict__ W1,  const float* __restrict__ b1,
    const float* __restrict__ W2,  const float* __restrict__ b2,
    const float* __restrict__ Wfc, const float* __restrict__ bfc,
    float* __restrict__ out)
{
    // ---- LDS: 155648 B total ----
    __shared__ __align__(16) f16 w1loL[16 * 2 * 64 * 8];   // 32 KB  A-frags of W1lo
    __shared__ __align__(16) f16 w2loL[4 * 8 * 64 * 8];    // 32 KB  A-frags of W2lo
    __shared__ __align__(16) f16 wfcL [2 * 2 * 64 * 8];    // 4 KB   A-frags of Wfc (f16)
    __shared__ __align__(16) f16 hhiB[4 * 16 * 264];       // 33 KB  per-PAIR h-hi
    __shared__ __align__(16) f16 hloB[4 * 16 * 264];       // 33 KB  per-PAIR h-lo
    __shared__ __align__(16) f16 khiB[4 * 16 * 72];        // 9 KB   per-PAIR k-hi
    __shared__ __align__(16) f16 kloB[4 * 16 * 72];        // 9 KB   per-PAIR k-lo

    const int tid  = (int)threadIdx.x;
    const int wid  = tid >> 6;
    const int lane = tid & 63;
    const int q    = lane >> 4;     // quad 0..3
    const int c    = lane & 15;     // lane-in-16 (batch row within tile)
    const int pair = wid >> 1;      // 0..3 : which 16-row group
    const int half = wid & 1;       // 0..1 : which half of H / D work
    const int g    = wid >> 2;      // phase group: 0 = wid 0..3, 1 = wid 4..7
    const int R0   = (int)blockIdx.x * 64 + pair * 16;
    const int jt0  = half * 8;      // GEMM1 H-tile range [jt0, jt0+8)
    const int dt0  = half * 2;      // GEMM2 D-tile range [dt0, dt0+2)

    f16* __restrict__ hhi = &hhiB[pair * 16 * 264];
    f16* __restrict__ hlo = &hloB[pair * 16 * 264];
    f16* __restrict__ khi = &khiB[pair * 16 * 72];
    f16* __restrict__ klo = &kloB[pair * 16 * 72];

    // ---------------- hi-weight A-fragments in registers ----------------
    // A-layout (16x16x32): lane holds A[m = tile*16 + c][k = ks*32 + q*8 + j]
    f16x8 w1a[8][2];    // W1T hi, jt = jt0 + j
#pragma unroll
    for (int j = 0; j < 8; ++j)
#pragma unroll
        for (int ks = 0; ks < 2; ++ks)
#pragma unroll
            for (int jj = 0; jj < 8; ++jj)
                w1a[j][ks][jj] = (f16)W1[(ks * 32 + q * 8 + jj) * 256 + (jt0 + j) * 16 + c];

    f16x8 w2a[2][8];    // W2T hi, dt = dt0 + d
#pragma unroll
    for (int d = 0; d < 2; ++d)
#pragma unroll
        for (int ks = 0; ks < 8; ++ks)
#pragma unroll
            for (int jj = 0; jj < 8; ++jj)
                w2a[d][ks][jj] = (f16)W2[(ks * 32 + q * 8 + jj) * 64 + (dt0 + d) * 16 + c];

    // ---------------- lo-weight A-fragments -> LDS (split across 8 waves) ----
    for (int jr = 0; jr < 2; ++jr) {
        int jt = wid * 2 + jr;
        for (int ks = 0; ks < 2; ++ks)
            for (int j = 0; j < 8; ++j) {
                float w = W1[(ks * 32 + q * 8 + j) * 256 + jt * 16 + c];
                f16 hi = (f16)w;
                w1loL[((jt * 2 + ks) * 64 + lane) * 8 + j] = (f16)(w - (float)hi);
            }
    }
    {
        int dt = wid >> 1;
        for (int kr = 0; kr < 4; ++kr) {
            int ks = (wid & 1) * 4 + kr;
            for (int j = 0; j < 8; ++j) {
                float w = W2[(ks * 32 + q * 8 + j) * 64 + dt * 16 + c];
                f16 hi = (f16)w;
                w2loL[((dt * 8 + ks) * 64 + lane) * 8 + j] = (f16)(w - (float)hi);
            }
        }
    }
    if (wid == 0)
        for (int ot = 0; ot < 2; ++ot)
            for (int ks = 0; ks < 2; ++ks)
                for (int j = 0; j < 8; ++j)
                    wfcL[((ot * 2 + ks) * 64 + lane) * 8 + j] =
                        (f16)Wfc[(ks * 32 + q * 8 + j) * 32 + ot * 16 + c];
    __syncthreads();   // weights become read-only after this

    // biases (persistent; b1 only needed at init)
    f32x4 b2v[2], bfcv;
#pragma unroll
    for (int d = 0; d < 2; ++d)
#pragma unroll
        for (int r = 0; r < 4; ++r) b2v[d][r] = b2[(dt0 + d) * 16 + 4 * q + r];
#pragma unroll
    for (int r = 0; r < 4; ++r) bfcv[r] = bfc[half * 16 + 4 * q + r];

    // ---------------- init from y0 (split hi+lo) ----------------
    f16x8 y0hi[2], y0lo[2];
#pragma unroll
    for (int ks = 0; ks < 2; ++ks)
#pragma unroll
        for (int j = 0; j < 8; ++j) {
            float v = y0g[(R0 + c) * 64 + ks * 32 + q * 8 + j];
            f16 hi = (f16)v;
            y0hi[ks][j] = hi;
            y0lo[ks][j] = (f16)(v - (float)hi);
        }

    f32x4 P1[8];
#pragma unroll
    for (int j = 0; j < 8; ++j) {
        f32x4 cc;
#pragma unroll
        for (int r = 0; r < 4; ++r) cc[r] = b1[(jt0 + j) * 16 + 4 * q + r];
#pragma unroll
        for (int ks = 0; ks < 2; ++ks) {
            f16x8 alo = *reinterpret_cast<const f16x8*>(&w1loL[(((jt0 + j) * 2 + ks) * 64 + lane) * 8]);
            cc = MFMA(w1a[j][ks], y0hi[ks], cc);
            cc = MFMA(w1a[j][ks], y0lo[ks], cc);
            cc = MFMA(alo,        y0hi[ks], cc);
        }
        P1[j] = cc;
    }
    // fc of y0: this wave produces output tile ot = half
    f32x4 pfc;
    {
        f32x4 z = {0.f, 0.f, 0.f, 0.f};
#pragma unroll
        for (int ks = 0; ks < 2; ++ks) {
            f16x8 wa = *reinterpret_cast<const f16x8*>(&wfcL[((half * 2 + ks) * 64 + lane) * 8]);
            z = MFMA(wa, y0hi[ks], z);
            z = MFMA(wa, y0lo[ks], z);
        }
        pfc = z;
    }
    {
        f32x4 v = pfc + bfcv;
        *reinterpret_cast<f32x4*>(&out[(size_t)(R0 + c) * 32 + half * 16 + 4 * q]) = v;
    }

    f32x4 ksum[2], dy[2];
#pragma unroll
    for (int d = 0; d < 2; ++d) dy[d] = f32x4{0.f, 0.f, 0.f, 0.f};

    // ---- bootstrap: h1 = tanh(P1) for this wave's jt half -> pair LDS ----
#pragma unroll
    for (int j = 0; j < 8; ++j) {
        float t0 = fast_tanh(P1[j][0]), t1 = fast_tanh(P1[j][1]);
        float t2 = fast_tanh(P1[j][2]), t3 = fast_tanh(P1[j][3]);
        f16x4 hv, lv;
        split4(t0, t1, t2, t3, &hv, &lv);
        *reinterpret_cast<f16x4*>(&hhi[c * 264 + (jt0 + j) * 16 + 4 * q]) = hv;
        *reinterpret_cast<f16x4*>(&hlo[c * 264 + (jt0 + j) * 16 + 4 * q]) = lv;
    }
    __syncthreads();

    // per-wave schedule scalars (wave-uniform -> SGPRs)
    int   ti = 0, r = 0;
    float dtv = tg[1] - tg[0];
    float hh  = dtv * 0.125f;
    float ch  = 0.5f * hh;
    float c6  = hh * (1.0f / 6.0f);

    // GEMM2 phase (D-split): k[dt0..dt0+1] = hhi@W2hi + hlo@W2hi + hhi@W2lo + b2
    auto gemm2body = [&](float w, bool first, bool last) {
        f32x4 ka[2];
#pragma unroll
        for (int d = 0; d < 2; ++d) ka[d] = b2v[d];
#pragma unroll
        for (int ks = 0; ks < 8; ++ks) {
            f16x8 bhi = *reinterpret_cast<const f16x8*>(&hhi[c * 264 + ks * 32 + q * 8]);
            f16x8 blo = *reinterpret_cast<const f16x8*>(&hlo[c * 264 + ks * 32 + q * 8]);
#pragma unroll
            for (int d = 0; d < 2; ++d) {
                f16x8 alo = *reinterpret_cast<const f16x8*>(&w2loL[(((dt0 + d) * 8 + ks) * 64 + lane) * 8]);
                ka[d] = MFMA(w2a[d][ks], bhi, ka[d]);
                ka[d] = MFMA(w2a[d][ks], blo, ka[d]);
                ka[d] = MFMA(alo,        bhi, ka[d]);
            }
        }
#pragma unroll
        for (int d = 0; d < 2; ++d) {
            if (first)      ksum[d] = ka[d];
            else            ksum[d] += ka[d] * w;
            f32x4 kv;
            if (!last) {
                kv = ka[d];
            } else {
                kv = ksum[d] * c6;
                dy[d] += kv;
            }
            f16x4 hv, lv;
            split4(kv[0], kv[1], kv[2], kv[3], &hv, &lv);
            *reinterpret_cast<f16x4*>(&khi[c * 72 + (dt0 + d) * 16 + 4 * q]) = hv;
            *reinterpret_cast<f16x4*>(&klo[c * 72 + (dt0 + d) * 16 + 4 * q]) = lv;
        }
    };

    // GEMM1 phase (H-split): z = W1T@k (full D); a = P1 + carg*z (or final:
    // P1 += z; a = P1); tanh; split -> pair h.
    auto gemm1body = [&](float carg, bool fin) {
        f16x8 kh0 = *reinterpret_cast<const f16x8*>(&khi[c * 72 + q * 8]);
        f16x8 kh1 = *reinterpret_cast<const f16x8*>(&khi[c * 72 + 32 + q * 8]);
        f16x8 kl0 = *reinterpret_cast<const f16x8*>(&klo[c * 72 + q * 8]);
        f16x8 kl1 = *reinterpret_cast<const f16x8*>(&klo[c * 72 + 32 + q * 8]);
#pragma unroll
        for (int j = 0; j < 8; ++j) {
            int jt = jt0 + j;
            f16x8 a0 = *reinterpret_cast<const f16x8*>(&w1loL[((jt * 2 + 0) * 64 + lane) * 8]);
            f16x8 a1 = *reinterpret_cast<const f16x8*>(&w1loL[((jt * 2 + 1) * 64 + lane) * 8]);
            f32x4 z = {0.f, 0.f, 0.f, 0.f};
            z = MFMA(w1a[j][0], kh0, z);
            z = MFMA(w1a[j][0], kl0, z);
            z = MFMA(a0,        kh0, z);
            z = MFMA(w1a[j][1], kh1, z);
            z = MFMA(w1a[j][1], kl1, z);
            z = MFMA(a1,        kh1, z);
            float a0f, a1f, a2f, a3f;
            if (fin) {
                P1[j] += z;
                a0f = P1[j][0]; a1f = P1[j][1]; a2f = P1[j][2]; a3f = P1[j][3];
            } else {
                a0f = __builtin_fmaf(carg, z[0], P1[j][0]);
                a1f = __builtin_fmaf(carg, z[1], P1[j][1]);
                a2f = __builtin_fmaf(carg, z[2], P1[j][2]);
                a3f = __builtin_fmaf(carg, z[3], P1[j][3]);
            }
            float t0 = fast_tanh(a0f), t1 = fast_tanh(a1f);
            float t2 = fast_tanh(a2f), t3 = fast_tanh(a3f);
            f16x4 hv, lv;
            split4(t0, t1, t2, t3, &hv, &lv);
            *reinterpret_cast<f16x4*>(&hhi[c * 264 + jt * 16 + 4 * q]) = hv;
            *reinterpret_cast<f16x4*>(&hlo[c * 264 + jt * 16 + 4 * q]) = lv;
        }
    };

    // interval epilogue A: dy split -> k buffers (pair exchange)
    auto epiA = [&]() {
#pragma unroll
        for (int d = 0; d < 2; ++d) {
            f16x4 hv, lv;
            split4(dy[d][0], dy[d][1], dy[d][2], dy[d][3], &hv, &lv);
            *reinterpret_cast<f16x4*>(&khi[c * 72 + (dt0 + d) * 16 + 4 * q]) = hv;
            *reinterpret_cast<f16x4*>(&klo[c * 72 + (dt0 + d) * 16 + 4 * q]) = lv;
            dy[d] = f32x4{0.f, 0.f, 0.f, 0.f};
        }
    };

    // interval epilogue B: pfc += dy @ Wfc; emit row ti+1
    auto epiB = [&]() {
        f16x8 dh0 = *reinterpret_cast<const f16x8*>(&khi[c * 72 + q * 8]);
        f16x8 dh1 = *reinterpret_cast<const f16x8*>(&khi[c * 72 + 32 + q * 8]);
        f16x8 dl0 = *reinterpret_cast<const f16x8*>(&klo[c * 72 + q * 8]);
        f16x8 dl1 = *reinterpret_cast<const f16x8*>(&klo[c * 72 + 32 + q * 8]);
        f16x8 wa0 = *reinterpret_cast<const f16x8*>(&wfcL[((half * 2 + 0) * 64 + lane) * 8]);
        f16x8 wa1 = *reinterpret_cast<const f16x8*>(&wfcL[((half * 2 + 1) * 64 + lane) * 8]);
        pfc = MFMA(wa0, dh0, pfc);
        pfc = MFMA(wa0, dl0, pfc);
        pfc = MFMA(wa1, dh1, pfc);
        pfc = MFMA(wa1, dl1, pfc);
        size_t base = (size_t)(ti + 1) * (16384 * 32);
        f32x4 v = pfc + bfcv;
        *reinterpret_cast<f32x4*>(&out[base + (size_t)(R0 + c) * 32 + half * 16 + 4 * q]) = v;
    };

    // ---------------- flattened phase loop with group offset ----------------
    // Phases per interval: 64 RK (8 substeps x {g2,g1,g2,g1,g2,g1,g2,g1}) + 2 epi.
    // Group 1 executes phase gp; group 0 executes phase gp-1. One barrier/slot.
    const int TOTAL = 49 * 66;
#pragma unroll 1
    for (int gp = 0; gp < TOTAL + 1; ++gp) {
        bool active = g ? (gp < TOTAL) : (gp >= 1);
        if (active) {
            if (r < 64) {
                int st = r & 7;
                int i  = st >> 1;
                if ((st & 1) == 0) {
                    float w = (i == 1 || i == 2) ? 2.0f : 1.0f;
                    gemm2body(w, i == 0, i == 3);
                } else {
                    float carg = (i < 2) ? ch : (i == 2 ? hh : 0.0f);
                    gemm1body(carg, i == 3);
                }
            } else if (r == 64) {
                epiA();
            } else {
                epiB();
            }
            ++r;
            if (r == 66) {
                r = 0; ++ti;
                if (ti < 49) {
                    float d2 = tg[ti + 1] - tg[ti];
                    hh = d2 * 0.125f;
                    ch = 0.5f * hh;
                    c6 = hh * (1.0f / 6.0f);
                }
            }
        }
        __syncthreads();
    }
}

extern "C" void kernel_launch(void* const* d_in, const int* in_sizes, int n_in,
                              void* d_out, int out_size, void* d_ws, size_t ws_size,
                              hipStream_t stream) {
    (void)in_sizes; (void)n_in; (void)d_ws; (void)ws_size; (void)out_size;
    const float* y0  = (const float*)d_in[0];
    const float* t   = (const float*)d_in[1];
    const float* W1  = (const float*)d_in[2];
    const float* b1  = (const float*)d_in[3];
    const float* W2  = (const float*)d_in[4];
    const float* b2  = (const float*)d_in[5];
    const float* Wfc = (const float*)d_in[6];
    const float* bfc = (const float*)d_in[7];
    float* out = (float*)d_out;
    // 256 blocks x 512 threads: 8 waves (2 groups x 2 pairs x 2 halves),
    // 1 block/CU, 2 waves/SIMD; group 1 phase-shifted by one half-stage.
    node_fused<<<dim3(256), dim3(512), 0, stream>>>(y0, t, W1, b1, W2, b2, Wfc, bfc, out);
}